// Round 1
// baseline (4024.082 us; speedup 1.0000x reference)
//
#include <hip/hip_runtime.h>

#define UNR _Pragma("unroll")

// ---------------------------------------------------------------------------
// Fused direct conv (+bias) + maxpool. One thread = one pooled output pixel,
// NCO consecutive output channels. cout group is block-uniform -> weight reads
// are scalar loads. Row-streamed input patch (PH x PH) to bound registers.
// ---------------------------------------------------------------------------
template<int CIN,int COUT,int K,int STRIDE,int PAD,int POOLK,int POOLS,int NCO,int INH,int BT>
__global__ __launch_bounds__(BT)
void convpool_k(const float* __restrict__ in, const float* __restrict__ w,
                const float* __restrict__ bias, float* __restrict__ out)
{
    constexpr int CONVH = (INH + 2*PAD - K)/STRIDE + 1;
    constexpr int POH   = (CONVH - POOLK)/POOLS + 1;
    constexpr int PH    = (POOLK-1)*STRIDE + K;   // input patch rows/cols
    constexpr int NPOS  = POOLK*POOLK;
    constexpr bool HOIST = (K*K*NCO <= 80);

    const int sp = blockIdx.x*BT + (int)threadIdx.x;
    if (sp >= POH*POH) return;
    const int ph = sp / POH, pw = sp % POH;
    const int co0 = blockIdx.y * NCO;
    const int b   = blockIdx.z;
    const int rowbase = ph*POOLS*STRIDE - PAD;
    const int colbase = pw*POOLS*STRIDE - PAD;

    float acc[NCO][NPOS];
    UNR for (int i=0;i<NCO;++i) UNR for (int j=0;j<NPOS;++j) acc[i][j]=0.f;

    for (int ci=0; ci<CIN; ++ci) {
        const float* ip = in + ((b*CIN+ci)*INH + rowbase)*INH + colbase;
        const float* wp = w + ((size_t)co0*CIN + ci)*K*K;   // + co*CIN*K*K
        float wreg[HOIST ? NCO*K*K : 1];
        if constexpr (HOIST) {
            UNR for (int co=0; co<NCO; ++co)
                UNR for (int kk=0; kk<K*K; ++kk)
                    wreg[co*K*K+kk] = wp[(size_t)co*CIN*K*K + kk];
        }
        UNR for (int ih=0; ih<PH; ++ih) {
            float px[PH];
            const int ir = rowbase + ih;
            UNR for (int iw=0; iw<PH; ++iw) {
                if constexpr (PAD > 0) {
                    const int ic = colbase + iw;
                    float v = 0.f;
                    if ((unsigned)ir < (unsigned)INH && (unsigned)ic < (unsigned)INH)
                        v = ip[ih*INH + iw];
                    px[iw] = v;
                } else {
                    px[iw] = ip[ih*INH + iw];
                }
            }
            UNR for (int dy=0; dy<POOLK; ++dy) {
                const int kh = ih - dy*STRIDE;       // folds at compile time
                if (kh >= 0 && kh < K) {
                    UNR for (int co=0; co<NCO; ++co) {
                        UNR for (int kw=0; kw<K; ++kw) {
                            const float wv = HOIST ? wreg[co*K*K + kh*K + kw]
                                                   : wp[(size_t)co*CIN*K*K + kh*K + kw];
                            UNR for (int dx=0; dx<POOLK; ++dx)
                                acc[co][dy*POOLK+dx] =
                                    fmaf(px[dx*STRIDE+kw], wv, acc[co][dy*POOLK+dx]);
                        }
                    }
                }
            }
        }
    }
    UNR for (int co=0; co<NCO; ++co) {
        float m = acc[co][0];
        UNR for (int j=1;j<NPOS;++j) m = fmaxf(m, acc[co][j]);
        out[(((size_t)b*COUT + co0+co)*POH + ph)*POH + pw] = m + bias[co0+co];
    }
}

// ---------------------------------------------------------------------------
// maxpool k=5 s=4 on (16,1024,10,10) -> (16,1024,2,2)
// ---------------------------------------------------------------------------
__global__ void pool54_k(const float* __restrict__ in, float* __restrict__ out) {
    int idx = blockIdx.x*256 + (int)threadIdx.x;
    if (idx >= 16*1024*4) return;
    int j = idx & 1, i = (idx>>1)&1, bc = idx>>2;
    const float* p = in + bc*100 + i*40 + j*4;
    float m = -1e30f;
    UNR for (int r=0;r<5;++r) UNR for (int c=0;c<5;++c) m = fmaxf(m, p[r*10+c]);
    out[idx] = m;
}

// ---------------------------------------------------------------------------
// bilinear 2x2 -> 7x7, zero-pad to 9x9, expanded directly into im2col form
// P[b][c][hw=49][k=9],  P[...] = padded_resized[b,c,h+i-1,w+j-1]
// ---------------------------------------------------------------------------
__device__ __forceinline__ void bigrid(int k, int& lo, float& f) {
    float c = ((float)k + 0.5f) * (2.0f/7.0f) - 0.5f;
    c = fminf(fmaxf(c, 0.f), 1.f);
    float fl = floorf(c);
    lo = (int)fl;
    f = c - fl;
}

__global__ void buildP_k(const float* __restrict__ pool, float* __restrict__ P) {
    int idx = blockIdx.x*256 + (int)threadIdx.x;   // exactly 7,225,344 threads
    int k  = idx % 9;
    int r_ = idx / 9;
    int hw = r_ % 49;
    int bc = r_ / 49;                 // b*1024+c
    int i = k/3, j = k%3;
    int h = hw/7, w2 = hw%7;
    int rr = h + i - 1, cc = w2 + j - 1;
    float val = 0.f;
    if (rr>=0 && rr<7 && cc>=0 && cc<7) {
        int rlo; float rf; bigrid(rr, rlo, rf);
        int clo; float cf; bigrid(cc, clo, cf);
        int rhi = min(rlo+1,1), chi = min(clo+1,1);
        const float* q = pool + bc*4;     // 2x2 plane
        float v00=q[rlo*2+clo], v01=q[rlo*2+chi], v10=q[rhi*2+clo], v11=q[rhi*2+chi];
        float top = v00*(1.f-cf) + v01*cf;
        float bot = v10*(1.f-cf) + v11*cf;
        val = top*(1.f-rf) + bot*rf;
    }
    P[idx] = val;
}

// ---------------------------------------------------------------------------
// Local conv partials: y[b,p] += sum_{c in split} P[b,c,hw,k]*lcw[c,p,k]
// p = o*49+hw (12544). 16 c-splits of 64. Weight reads: lane-contiguous 36B
// chunks -> fully coalesced; lcw streamed from HBM exactly once.
// ---------------------------------------------------------------------------
__global__ __launch_bounds__(256)
void lconv_k(const float* __restrict__ P, const float* __restrict__ lcw,
             float* __restrict__ part) {
    const int p = blockIdx.x*256 + (int)threadIdx.x;   // 0..12543
    const int s = blockIdx.y;                          // 0..15
    const int pb = (p % 49)*9;
    float acc[16];
    UNR for (int b=0;b<16;++b) acc[b]=0.f;
    const int c0 = s*64;
    for (int c=c0; c<c0+64; ++c) {
        const float* wp = lcw + (size_t)c*112896 + p*9;
        float wv[9];
        UNR for (int k=0;k<9;++k) wv[k]=wp[k];
        const float* pp = P + (size_t)c*441 + pb;
        UNR for (int b=0;b<16;++b) {
            const float* q = pp + (size_t)b*451584;
            float t = 0.f;
            UNR for (int k=0;k<9;++k) t = fmaf(q[k], wv[k], t);
            acc[b] += t;
        }
    }
    UNR for (int b=0;b<16;++b)
        part[((size_t)(s*16+b))*12544 + p] = acc[b];
}

__global__ void lreduce_k(const float* __restrict__ part, const float* __restrict__ lcb,
                          float* __restrict__ yact) {
    int idx = blockIdx.x*256 + (int)threadIdx.x;  // 200704 exactly
    int p = idx % 12544, b = idx / 12544;
    float sum = 0.f;
    UNR for (int s=0;s<16;++s) sum += part[((size_t)(s*16+b))*12544 + p];
    sum += lcb[p];
    yact[idx] = (sum > 0.f) ? sum : 0.1f*sum;
}

// ---------------------------------------------------------------------------
// FC: y[b,o] = act[b,:]·fc_w[o,:] + fc_b[o].  Block = 256 threads = k-lanes,
// NO=4 outputs/block, act chunk staged in LDS, shuffle-tree reduction.
// ---------------------------------------------------------------------------
__global__ __launch_bounds__(256)
void fc_k(const float* __restrict__ act, const float* __restrict__ fw,
          const float* __restrict__ fb, float* __restrict__ out) {
    __shared__ float alds[16][256];
    __shared__ float red[4][4][16];
    const int t = (int)threadIdx.x;
    const int o0 = blockIdx.x*4;
    float acc[4][16];
    UNR for (int oo=0;oo<4;++oo) UNR for (int b=0;b<16;++b) acc[oo][b]=0.f;

    for (int k0=0; k0<12544; k0+=256) {
        __syncthreads();
        UNR for (int b=0;b<16;++b) alds[b][t] = act[b*12544 + k0 + t];
        __syncthreads();
        float wv[4];
        UNR for (int oo=0;oo<4;++oo) {
            int o = o0+oo;
            wv[oo] = (o < 4949) ? fw[(size_t)o*12544 + k0 + t] : 0.f;
        }
        UNR for (int b=0;b<16;++b) {
            float av = alds[b][t];
            UNR for (int oo=0;oo<4;++oo) acc[oo][b] = fmaf(wv[oo], av, acc[oo][b]);
        }
    }
    // wave reduce each of the 64 partials
    UNR for (int oo=0;oo<4;++oo)
        UNR for (int b=0;b<16;++b) {
            float v = acc[oo][b];
            UNR for (int off=32; off; off>>=1) v += __shfl_xor(v, off, 64);
            acc[oo][b] = v;
        }
    const int wave = t>>6, lane = t&63;
    if (lane == 0)
        UNR for (int oo=0;oo<4;++oo)
            UNR for (int b=0;b<16;++b) red[wave][oo][b] = acc[oo][b];
    __syncthreads();
    if (t < 64) {
        int oo = t>>4, b = t&15;
        float v = red[0][oo][b]+red[1][oo][b]+red[2][oo][b]+red[3][oo][b];
        int o = o0+oo;
        if (o < 4949) out[b*4949 + o] = v + fb[o];
    }
}

// ---------------------------------------------------------------------------
extern "C" void kernel_launch(void* const* d_in, const int* in_sizes, int n_in,
                              void* d_out, int out_size, void* d_ws, size_t ws_size,
                              hipStream_t stream) {
    const float* x   = (const float*)d_in[0];
    const float* w1  = (const float*)d_in[1];
    const float* b1  = (const float*)d_in[2];
    const float* w3  = (const float*)d_in[3];
    const float* b3  = (const float*)d_in[4];
    const float* w4  = (const float*)d_in[5];
    const float* b4  = (const float*)d_in[6];
    const float* w7  = (const float*)d_in[7];
    const float* b7  = (const float*)d_in[8];
    const float* w8  = (const float*)d_in[9];
    const float* b8  = (const float*)d_in[10];
    const float* wu  = (const float*)d_in[11];
    const float* bu  = (const float*)d_in[12];
    const float* lcw = (const float*)d_in[13];
    const float* lcb = (const float*)d_in[14];
    const float* fw  = (const float*)d_in[15];
    const float* fb  = (const float*)d_in[16];
    float* out = (float*)d_out;

    // workspace ping-pong (needs ~90 MB): R0 = 12,845,056 f, R1 = 9,633,792 f
    float* R0 = (float*)d_ws;
    float* R1 = R0 + 12845056;
    float* part = R1;              // 16*16*12544 = 3,211,264 f
    float* yact = R1 + 3211264;    // 200,704 f

    // conv1 7x7 s2 p3 (3->64) + pool2  : (16,3,448,448) -> (16,64,112,112)
    convpool_k<3,64,7,2,3,2,2,4,448,256><<<dim3(49,16,16),256,0,stream>>>(x,  w1, b1, R0);
    // conv3 3x3 p1 (64->192) + pool2   : -> (16,192,56,56)
    convpool_k<64,192,3,1,1,2,2,8,112,64><<<dim3(49,24,16),64,0,stream>>>(R0, w3, b3, R1);
    // conv4 3x3 p0 (192->256) + pool2  : -> (16,256,27,27)
    convpool_k<192,256,3,1,0,2,2,8,56,64><<<dim3(12,32,16),64,0,stream>>>(R1, w4, b4, R0);
    // conv7 2x2 (256->512) + pool2     : -> (16,512,13,13)
    convpool_k<256,512,2,1,0,2,2,8,27,64><<<dim3(3,64,16),64,0,stream>>>(R0, w7, b7, R1);
    // conv8 2x2 (512->1024)            : -> (16,1024,12,12)
    convpool_k<512,1024,2,1,0,1,1,16,13,64><<<dim3(3,64,16),64,0,stream>>>(R1, w8, b8, R0);
    // convu 2x2 (1024->1024)           : -> (16,1024,11,11)
    convpool_k<1024,1024,2,1,0,1,1,16,12,64><<<dim3(2,64,16),64,0,stream>>>(R0, wu, bu, R1);
    // convu 2x2 (1024->1024)           : -> (16,1024,10,10)
    convpool_k<1024,1024,2,1,0,1,1,16,11,64><<<dim3(2,64,16),64,0,stream>>>(R1, wu, bu, R0);
    // maxpool 5,4                      : -> (16,1024,2,2)
    pool54_k<<<256,256,0,stream>>>(R0, R1);
    // bilinear 2->7 + pad + im2col     : -> P (16,1024,49,9) in R0
    buildP_k<<<28224,256,0,stream>>>(R1, R0);
    // local conv partials (16 c-splits)
    lconv_k<<<dim3(49,16),256,0,stream>>>(R0, lcw, part);
    // reduce + bias + leaky relu       : -> yact (16,12544)
    lreduce_k<<<784,256,0,stream>>>(part, lcb, yact);
    // fully connected                  : -> out (16,4949)
    fc_k<<<1238,256,0,stream>>>(yact, fw, fb, out);
}

// Round 2
// 1527.512 us; speedup vs baseline: 2.6344x; 2.6344x over previous
//
#include <hip/hip_runtime.h>

#define UNR _Pragma("unroll")

typedef __attribute__((ext_vector_type(8))) short short8v;
typedef __attribute__((ext_vector_type(4))) float f32x4;

__device__ __forceinline__ ushort f2bf(float f) {
    union { float f; unsigned u; } x; x.f = f;
    unsigned r = (x.u + 0x7fffu + ((x.u >> 16) & 1u)) >> 16;
    return (ushort)r;
}
__device__ __forceinline__ float bf2f(ushort u) {
    union { unsigned u; float f; } x; x.u = ((unsigned)u) << 16;
    return x.f;
}

// ---------------------------------------------------------------------------
// MFMA implicit-GEMM conv, NHWC bf16 activations, fused 2x2/s2 maxpool.
// GEMM: D[co][n] = sum_k W[co][k] * X[n][k],   k = (ky,kx,ci), ci contiguous.
// n = pooled_pos*4 + quadrant (POOL) or flat (b,oy,ox).
// Wave computes 64co x 64n via 4x4 frags of mfma_f32_16x16x32_bf16.
// A-frag: lane supplies A[l&15][8*(l>>4)+e]; B-frag: B[8*(l>>4)+e][l&15];
// D: lane holds D[4*(l>>4)+reg][l&15]  (m89-verified C/D layout).
// ---------------------------------------------------------------------------
template<int CIN,int K,int STRIDE,int Wp,int Hp,int OW,int OH,int COUT,
         bool POOL,int WpN,int HpN,int PADN,int CN,int WAVES,bool CI4>
__global__ __launch_bounds__(WAVES*64)
void convmf(const ushort* __restrict__ Xp, const ushort* __restrict__ Wb,
            const float* __restrict__ bias, ushort* __restrict__ Yp)
{
    constexpr int KK   = CI4 ? 224 : K*K*CIN;
    constexpr int POW  = OW/2, POH = OH/2;
    constexpr int NTOT = POOL ? 16*POW*POH*4 : 16*OW*OH;

    const int lane = (int)threadIdx.x & 63;
    const int wave = (int)threadIdx.x >> 6;
    const int n0   = (blockIdx.x*WAVES + wave) * 64;
    const int co0  = blockIdx.y * 64;
    const int lm   = lane & 15;   // A-row / B-col / D-col
    const int lk   = lane >> 4;   // k-group

    unsigned boff[4];
    int ns[4];
    UNR for (int nf=0; nf<4; ++nf) {
        int n = n0 + nf*16 + lm;
        if (n > NTOT-1) n = NTOT-1;
        ns[nf] = n;
        int b, oy, ox;
        if constexpr (POOL) {
            int q = n & 3, pp = n >> 2;
            int px = pp % POW; int t = pp / POW;
            int py = t % POH;  b = t / POH;
            oy = 2*py + (q>>1); ox = 2*px + (q&1);
        } else {
            ox = n % OW; int t = n / OW; oy = t % OH; b = t / OH;
        }
        boff[nf] = ((unsigned)(b*Hp + oy*STRIDE)*Wp + (unsigned)(ox*STRIDE))*CIN
                 + 8u*lk;
    }
    const unsigned abase = (unsigned)(co0 + lm)*KK + 8u*lk;

    f32x4 acc[4][4];
    UNR for (int i=0;i<4;++i) UNR for (int j=0;j<4;++j) acc[i][j] = f32x4{0.f,0.f,0.f,0.f};

    auto step = [&](unsigned aoff, unsigned xoff) {
        short8v a[4], bf[4];
        UNR for (int mf=0; mf<4; ++mf)
            a[mf] = *(const short8v*)(Wb + abase + aoff + (unsigned)mf*16u*KK);
        UNR for (int nf=0; nf<4; ++nf)
            bf[nf] = *(const short8v*)(Xp + boff[nf] + xoff);
        UNR for (int mf=0; mf<4; ++mf)
            UNR for (int nf=0; nf<4; ++nf)
                acc[mf][nf] = __builtin_amdgcn_mfma_f32_16x16x32_bf16(
                                  a[mf], bf[nf], acc[mf][nf], 0, 0, 0);
    };

    if constexpr (CI4) {
        // conv1: one K-step = one ky row (kx0..7 x ci0..3 packed, padded zeros)
        UNR for (int ky=0; ky<7; ++ky)
            step((unsigned)(ky*32), (unsigned)(ky*Wp)*4u);
    } else {
        UNR for (int ky=0; ky<K; ++ky)
            UNR for (int kx=0; kx<K; ++kx)
                for (int c0=0; c0<CIN; c0+=32)
                    step((unsigned)((ky*K+kx)*CIN + c0),
                         (unsigned)((ky*Wp+kx)*CIN + c0));
    }

    // epilogue: +bias, (pool via shfl), bf16 store into padded NHWC next input
    UNR for (int mf=0; mf<4; ++mf) {
        const int co = co0 + mf*16 + 4*lk;
        f32x4 bi = *(const f32x4*)(bias + co);
        UNR for (int nf=0; nf<4; ++nf) {
            f32x4 v = acc[mf][nf];
            UNR for (int r=0;r<4;++r) v[r] += bi[r];
            if constexpr (POOL) {
                UNR for (int r=0;r<4;++r) {
                    float t = v[r];
                    t = fmaxf(t, __shfl_xor(t, 1, 64));
                    t = fmaxf(t, __shfl_xor(t, 2, 64));
                    v[r] = t;
                }
                if ((lane & 3) == 0 && (n0 + nf*16 + lm) < NTOT) {
                    int pp = ns[nf] >> 2;
                    int px = pp % POW; int t2 = pp / POW;
                    int py = t2 % POH; int b = t2 / POH;
                    unsigned off = ((unsigned)(b*HpN + py + PADN)*WpN
                                    + (unsigned)(px + PADN))*CN + co;
                    ushort4 s; s.x=f2bf(v[0]); s.y=f2bf(v[1]); s.z=f2bf(v[2]); s.w=f2bf(v[3]);
                    *(ushort4*)(Yp + off) = s;
                }
            } else {
                if ((n0 + nf*16 + lm) < NTOT) {
                    int n = ns[nf];
                    int ox = n % OW; int t2 = n / OW; int oy = t2 % OH; int b = t2 / OH;
                    unsigned off = ((unsigned)(b*HpN + oy)*WpN + (unsigned)ox)*CN + co;
                    ushort4 s; s.x=f2bf(v[0]); s.y=f2bf(v[1]); s.z=f2bf(v[2]); s.w=f2bf(v[3]);
                    *(ushort4*)(Yp + off) = s;
                }
            }
        }
    }
}

// ---------------------------------------------------------------------------
// input build: x (16,3,448,448) f32 -> X1 bf16 [b][y+3][x+3][ci(4)], padded 456x456
// ---------------------------------------------------------------------------
__global__ void x1build(const float* __restrict__ x, ushort* __restrict__ X1) {
    int idx = blockIdx.x*256 + (int)threadIdx.x;      // 16*448*448 exactly
    int xx = idx % 448; int t = idx/448; int y = t % 448; int b = t/448;
    const float* px = x + ((size_t)b*3*448 + y)*448 + xx;
    ushort4 s;
    s.x = f2bf(px[0]); s.y = f2bf(px[200704]); s.z = f2bf(px[401408]); s.w = 0;
    *(ushort4*)(X1 + ((unsigned)(b*456 + y+3)*456 + (unsigned)(xx+3))*4) = s;
}

// w1 (64,3,7,7) f32 -> W1b [co][ky*32 + kx*4 + ci] bf16 (zeros at kx==7 / ci==3)
__global__ void wcvt1(const float* __restrict__ w, ushort* __restrict__ o) {
    int idx = blockIdx.x*256 + (int)threadIdx.x;      // 64*224 = 14336
    if (idx >= 64*224) return;
    int r = idx % 224; int co = idx / 224;
    int ky = r / 32; int t = r % 32; int kx = t / 4; int ci = t % 4;
    float v = 0.f;
    if (kx < 7 && ci < 3) v = w[(((size_t)co*3 + ci)*7 + ky)*7 + kx];
    o[idx] = f2bf(v);
}

// generic OIHW f32 -> [co][ky][kx][ci] bf16
template<int CIN,int K>
__global__ void wcvt(const float* __restrict__ w, ushort* __restrict__ o, int total) {
    int idx = blockIdx.x*256 + (int)threadIdx.x;
    if (idx >= total) return;
    int ci = idx % CIN; int t = idx / CIN;
    int kx = t % K; t /= K; int ky = t % K; int co = t / K;
    o[idx] = f2bf(w[(((size_t)co*CIN + ci)*K + ky)*K + kx]);
}

// ---------------------------------------------------------------------------
// maxpool k=5 s=4: XU3 bf16 NHWC (16,10,10,1024) -> pp f32 [b*1024+c][4]
// ---------------------------------------------------------------------------
__global__ void pool54_k(const ushort* __restrict__ in, float* __restrict__ out) {
    int idx = blockIdx.x*256 + (int)threadIdx.x;      // 16*4*1024 = 65536
    int c = idx & 1023; int t = idx >> 10; int q = t & 3; int b = t >> 2;
    int i = q >> 1, j = q & 1;
    float m = -1e30f;
    UNR for (int r=0;r<5;++r)
        UNR for (int cc=0;cc<5;++cc)
            m = fmaxf(m, bf2f(in[(((unsigned)(b*10 + i*4+r))*10 + (unsigned)(j*4+cc))*1024 + c]));
    out[((size_t)(b*1024 + c))*4 + q] = m;
}

// ---------------------------------------------------------------------------
// bilinear 2x2->7x7, pad, im2col:  P[b*1024+c][hw=49][k=9]  (f32)
// ---------------------------------------------------------------------------
__device__ __forceinline__ void bigrid(int k, int& lo, float& f) {
    float c = ((float)k + 0.5f) * (2.0f/7.0f) - 0.5f;
    c = fminf(fmaxf(c, 0.f), 1.f);
    float fl = floorf(c);
    lo = (int)fl;
    f = c - fl;
}

__global__ void buildP_k(const float* __restrict__ pool, float* __restrict__ P) {
    int idx = blockIdx.x*256 + (int)threadIdx.x;   // 7,225,344 exactly
    int k  = idx % 9;
    int r_ = idx / 9;
    int hw = r_ % 49;
    int bc = r_ / 49;
    int i = k/3, j = k%3;
    int h = hw/7, w2 = hw%7;
    int rr = h + i - 1, cc = w2 + j - 1;
    float val = 0.f;
    if (rr>=0 && rr<7 && cc>=0 && cc<7) {
        int rlo; float rf; bigrid(rr, rlo, rf);
        int clo; float cf; bigrid(cc, clo, cf);
        int rhi = min(rlo+1,1), chi = min(clo+1,1);
        const float* q = pool + (size_t)bc*4;
        float v00=q[rlo*2+clo], v01=q[rlo*2+chi], v10=q[rhi*2+clo], v11=q[rhi*2+chi];
        float top = v00*(1.f-cf) + v01*cf;
        float bot = v10*(1.f-cf) + v11*cf;
        val = top*(1.f-rf) + bot*rf;
    }
    P[idx] = val;
}

// ---------------------------------------------------------------------------
// Local conv partials (16 c-splits of 64), then reduce + bias + leaky relu
// ---------------------------------------------------------------------------
__global__ __launch_bounds__(256)
void lconv_k(const float* __restrict__ P, const float* __restrict__ lcw,
             float* __restrict__ part) {
    const int p = blockIdx.x*256 + (int)threadIdx.x;   // 0..12543
    const int s = blockIdx.y;                          // 0..15
    const int pb = (p % 49)*9;
    float acc[16];
    UNR for (int b=0;b<16;++b) acc[b]=0.f;
    const int c0 = s*64;
    for (int c=c0; c<c0+64; ++c) {
        const float* wp = lcw + (size_t)c*112896 + p*9;
        float wv[9];
        UNR for (int k=0;k<9;++k) wv[k]=wp[k];
        const float* pp = P + (size_t)c*441 + pb;
        UNR for (int b=0;b<16;++b) {
            const float* q = pp + (size_t)b*451584;
            float t = 0.f;
            UNR for (int k=0;k<9;++k) t = fmaf(q[k], wv[k], t);
            acc[b] += t;
        }
    }
    UNR for (int b=0;b<16;++b)
        part[((size_t)(s*16+b))*12544 + p] = acc[b];
}

__global__ void lreduce_k(const float* __restrict__ part, const float* __restrict__ lcb,
                          float* __restrict__ yact) {
    int idx = blockIdx.x*256 + (int)threadIdx.x;  // 200704 exactly
    int p = idx % 12544, b = idx / 12544;
    float sum = 0.f;
    UNR for (int s=0;s<16;++s) sum += part[((size_t)(s*16+b))*12544 + p];
    sum += lcb[p];
    yact[idx] = (sum > 0.f) ? sum : 0.1f*sum;
}

// ---------------------------------------------------------------------------
// FC
// ---------------------------------------------------------------------------
__global__ __launch_bounds__(256)
void fc_k(const float* __restrict__ act, const float* __restrict__ fw,
          const float* __restrict__ fb, float* __restrict__ out) {
    __shared__ float alds[16][256];
    __shared__ float red[4][4][16];
    const int t = (int)threadIdx.x;
    const int o0 = blockIdx.x*4;
    float acc[4][16];
    UNR for (int oo=0;oo<4;++oo) UNR for (int b=0;b<16;++b) acc[oo][b]=0.f;

    for (int k0=0; k0<12544; k0+=256) {
        __syncthreads();
        UNR for (int b=0;b<16;++b) alds[b][t] = act[b*12544 + k0 + t];
        __syncthreads();
        float wv[4];
        UNR for (int oo=0;oo<4;++oo) {
            int o = o0+oo;
            wv[oo] = (o < 4949) ? fw[(size_t)o*12544 + k0 + t] : 0.f;
        }
        UNR for (int b=0;b<16;++b) {
            float av = alds[b][t];
            UNR for (int oo=0;oo<4;++oo) acc[oo][b] = fmaf(wv[oo], av, acc[oo][b]);
        }
    }
    UNR for (int oo=0;oo<4;++oo)
        UNR for (int b=0;b<16;++b) {
            float v = acc[oo][b];
            UNR for (int off=32; off; off>>=1) v += __shfl_xor(v, off, 64);
            acc[oo][b] = v;
        }
    const int wave = t>>6, lane = t&63;
    if (lane == 0)
        UNR for (int oo=0;oo<4;++oo)
            UNR for (int b=0;b<16;++b) red[wave][oo][b] = acc[oo][b];
    __syncthreads();
    if (t < 64) {
        int oo = t>>4, b = t&15;
        float v = red[0][oo][b]+red[1][oo][b]+red[2][oo][b]+red[3][oo][b];
        int o = o0+oo;
        if (o < 4949) out[b*4949 + o] = v + fb[o];
    }
}

// ---------------------------------------------------------------------------
extern "C" void kernel_launch(void* const* d_in, const int* in_sizes, int n_in,
                              void* d_out, int out_size, void* d_ws, size_t ws_size,
                              hipStream_t stream) {
    const float* x   = (const float*)d_in[0];
    const float* w1  = (const float*)d_in[1];
    const float* b1  = (const float*)d_in[2];
    const float* w3  = (const float*)d_in[3];
    const float* b3  = (const float*)d_in[4];
    const float* w4  = (const float*)d_in[5];
    const float* b4  = (const float*)d_in[6];
    const float* w7  = (const float*)d_in[7];
    const float* b7  = (const float*)d_in[8];
    const float* w8  = (const float*)d_in[9];
    const float* b8  = (const float*)d_in[10];
    const float* wu  = (const float*)d_in[11];
    const float* bu  = (const float*)d_in[12];
    const float* lcw = (const float*)d_in[13];
    const float* lcb = (const float*)d_in[14];
    const float* fw  = (const float*)d_in[15];
    const float* fb  = (const float*)d_in[16];
    float* out = (float*)d_out;

    // --- workspace carve (bytes, 256-aligned) ---
    char* base = (char*)d_ws;
    auto alloc = [&](size_t bytes) { char* p = base; base += (bytes + 255) & ~(size_t)255; return p; };
    ushort* X1  = (ushort*)alloc(16u*456*456*4*2);   // 26.6 MB (later reused as P)
    ushort* X3  = (ushort*)alloc(16u*114*114*64*2);  // 26.6 MB
    ushort* X4  = (ushort*)alloc(16u*56*56*192*2);   // 19.3 MB (later reused as part)
    ushort* X7  = (ushort*)alloc(16u*27*27*256*2);   // 6.0 MB (later reused as yact)
    ushort* X8  = (ushort*)alloc(16u*13*13*512*2);
    ushort* XU1 = (ushort*)alloc(16u*12*12*1024*2);
    ushort* XU2 = (ushort*)alloc(16u*11*11*1024*2);
    ushort* XU3 = (ushort*)alloc(16u*10*10*1024*2);
    ushort* W1b = (ushort*)alloc(64u*224*2);
    ushort* W3b = (ushort*)alloc(192u*576*2);
    ushort* W4b = (ushort*)alloc(256u*1728*2);
    ushort* W7b = (ushort*)alloc(512u*1024*2);
    ushort* W8b = (ushort*)alloc(1024u*2048*2);
    ushort* WUb = (ushort*)alloc(1024u*4096*2);
    float*  pp  = (float*)alloc(16u*1024*4*4);
    // aliased (lifetimes disjoint):
    float*  P    = (float*)X1;   // 28.9 MB over X1+X3 (both dead by then)
    float*  part = (float*)X4;   // 12.8 MB over X4 (dead)
    float*  yact = (float*)X7;   // 0.8 MB over X7 (dead)

    // --- prep: zero padded buffers, convert input & weights to bf16 ---
    hipMemsetAsync(X1, 0, 16u*456*456*4*2, stream);
    hipMemsetAsync(X3, 0, 16u*114*114*64*2, stream);
    x1build<<<12544, 256, 0, stream>>>(x, X1);
    wcvt1<<<56, 256, 0, stream>>>(w1, W1b);
    wcvt<64,3><<<432, 256, 0, stream>>>(w3, W3b, 192*576);
    wcvt<192,3><<<1728, 256, 0, stream>>>(w4, W4b, 256*1728);
    wcvt<256,2><<<2048, 256, 0, stream>>>(w7, W7b, 512*1024);
    wcvt<512,2><<<8192, 256, 0, stream>>>(w8, W8b, 1024*2048);
    wcvt<1024,2><<<16384, 256, 0, stream>>>(wu, WUb, 1024*4096);

    // --- conv chain (MFMA, fused pool) ---
    // conv1 7x7 s2 p3 (3->64) +pool -> X3 [16][114][114][64], pad 1
    convmf<4,7,2,456,456,224,224,64, true,114,114,1,64, 4,true>
        <<<dim3(3136,1), 256, 0, stream>>>(X1, W1b, b1, X3);
    // conv3 3x3 p1 (64->192) +pool -> X4 [16][56][56][192]
    convmf<64,3,1,114,114,112,112,192, true,56,56,0,192, 4,false>
        <<<dim3(784,3), 256, 0, stream>>>(X3, W3b, b3, X4);
    // conv4 3x3 (192->256) +pool -> X7 [16][27][27][256]
    convmf<192,3,1,56,56,54,54,256, true,27,27,0,256, 4,false>
        <<<dim3(183,4), 256, 0, stream>>>(X4, W4b, b4, X7);
    // conv7 2x2 (256->512) +pool -> X8 [16][13][13][512]
    convmf<256,2,1,27,27,26,26,512, true,13,13,0,512, 1,false>
        <<<dim3(169,8), 64, 0, stream>>>(X7, W7b, b7, X8);
    // conv8 2x2 (512->1024) -> XU1 [16][12][12][1024]
    convmf<512,2,1,13,13,12,12,1024, false,12,12,0,1024, 1,false>
        <<<dim3(36,16), 64, 0, stream>>>(X8, W8b, b8, XU1);
    // convu 2x2 (1024->1024) -> XU2 [16][11][11][1024]
    convmf<1024,2,1,12,12,11,11,1024, false,11,11,0,1024, 1,false>
        <<<dim3(31,16), 64, 0, stream>>>(XU1, WUb, bu, XU2);
    // convu 2x2 (1024->1024) -> XU3 [16][10][10][1024]
    convmf<1024,2,1,11,11,10,10,1024, false,10,10,0,1024, 1,false>
        <<<dim3(25,16), 64, 0, stream>>>(XU2, WUb, bu, XU3);

    // --- head (fp32) ---
    pool54_k<<<256, 256, 0, stream>>>(XU3, pp);
    buildP_k<<<28224, 256, 0, stream>>>(pp, P);
    lconv_k<<<dim3(49,16), 256, 0, stream>>>(P, lcw, part);
    lreduce_k<<<784, 256, 0, stream>>>(part, lcb, yact);
    fc_k<<<1238, 256, 0, stream>>>(yact, fw, fb, out);
}

// Round 3
// 1310.851 us; speedup vs baseline: 3.0698x; 1.1653x over previous
//
#include <hip/hip_runtime.h>

#define UNR _Pragma("unroll")

typedef __attribute__((ext_vector_type(8))) short short8v;
typedef __attribute__((ext_vector_type(4))) float f32x4;

__device__ __forceinline__ ushort f2bf(float f) {
    union { float f; unsigned u; } x; x.f = f;
    unsigned r = (x.u + 0x7fffu + ((x.u >> 16) & 1u)) >> 16;
    return (ushort)r;
}
__device__ __forceinline__ float bf2f(ushort u) {
    union { unsigned u; float f; } x; x.u = ((unsigned)u) << 16;
    return x.f;
}

// ---------------------------------------------------------------------------
// MFMA implicit-GEMM conv, NHWC bf16 activations, fused 2x2/s2 maxpool.
// ---------------------------------------------------------------------------
template<int CIN,int K,int STRIDE,int Wp,int Hp,int OW,int OH,int COUT,
         bool POOL,int WpN,int HpN,int PADN,int CN,int WAVES,bool CI4>
__global__ __launch_bounds__(WAVES*64)
void convmf(const ushort* __restrict__ Xp, const ushort* __restrict__ Wb,
            const float* __restrict__ bias, ushort* __restrict__ Yp)
{
    constexpr int KK   = CI4 ? 224 : K*K*CIN;
    constexpr int POW  = OW/2, POH = OH/2;
    constexpr int NTOT = POOL ? 16*POW*POH*4 : 16*OW*OH;

    const int lane = (int)threadIdx.x & 63;
    const int wave = (int)threadIdx.x >> 6;
    const int n0   = (blockIdx.x*WAVES + wave) * 64;
    const int co0  = blockIdx.y * 64;
    const int lm   = lane & 15;   // A-row / B-col / D-col
    const int lk   = lane >> 4;   // k-group

    unsigned boff[4];
    int ns[4];
    UNR for (int nf=0; nf<4; ++nf) {
        int n = n0 + nf*16 + lm;
        if (n > NTOT-1) n = NTOT-1;
        ns[nf] = n;
        int b, oy, ox;
        if constexpr (POOL) {
            int q = n & 3, pp = n >> 2;
            int px = pp % POW; int t = pp / POW;
            int py = t % POH;  b = t / POH;
            oy = 2*py + (q>>1); ox = 2*px + (q&1);
        } else {
            ox = n % OW; int t = n / OW; oy = t % OH; b = t / OH;
        }
        boff[nf] = ((unsigned)(b*Hp + oy*STRIDE)*Wp + (unsigned)(ox*STRIDE))*CIN
                 + 8u*lk;
    }
    const unsigned abase = (unsigned)(co0 + lm)*KK + 8u*lk;

    f32x4 acc[4][4];
    UNR for (int i=0;i<4;++i) UNR for (int j=0;j<4;++j) acc[i][j] = f32x4{0.f,0.f,0.f,0.f};

    auto step = [&](unsigned aoff, unsigned xoff) {
        short8v a[4], bf[4];
        UNR for (int mf=0; mf<4; ++mf)
            a[mf] = *(const short8v*)(Wb + abase + aoff + (unsigned)mf*16u*KK);
        UNR for (int nf=0; nf<4; ++nf)
            bf[nf] = *(const short8v*)(Xp + boff[nf] + xoff);
        UNR for (int mf=0; mf<4; ++mf)
            UNR for (int nf=0; nf<4; ++nf)
                acc[mf][nf] = __builtin_amdgcn_mfma_f32_16x16x32_bf16(
                                  a[mf], bf[nf], acc[mf][nf], 0, 0, 0);
    };

    if constexpr (CI4) {
        UNR for (int ky=0; ky<7; ++ky)
            step((unsigned)(ky*32), (unsigned)(ky*Wp)*4u);
    } else {
        UNR for (int ky=0; ky<K; ++ky)
            UNR for (int kx=0; kx<K; ++kx)
                for (int c0=0; c0<CIN; c0+=32)
                    step((unsigned)((ky*K+kx)*CIN + c0),
                         (unsigned)((ky*Wp+kx)*CIN + c0));
    }

    UNR for (int mf=0; mf<4; ++mf) {
        const int co = co0 + mf*16 + 4*lk;
        f32x4 bi = *(const f32x4*)(bias + co);
        UNR for (int nf=0; nf<4; ++nf) {
            f32x4 v = acc[mf][nf];
            UNR for (int r=0;r<4;++r) v[r] += bi[r];
            if constexpr (POOL) {
                UNR for (int r=0;r<4;++r) {
                    float t = v[r];
                    t = fmaxf(t, __shfl_xor(t, 1, 64));
                    t = fmaxf(t, __shfl_xor(t, 2, 64));
                    v[r] = t;
                }
                if ((lane & 3) == 0 && (n0 + nf*16 + lm) < NTOT) {
                    int pp = ns[nf] >> 2;
                    int px = pp % POW; int t2 = pp / POW;
                    int py = t2 % POH; int b = t2 / POH;
                    unsigned off = ((unsigned)(b*HpN + py + PADN)*WpN
                                    + (unsigned)(px + PADN))*CN + co;
                    ushort4 s; s.x=f2bf(v[0]); s.y=f2bf(v[1]); s.z=f2bf(v[2]); s.w=f2bf(v[3]);
                    *(ushort4*)(Yp + off) = s;
                }
            } else {
                if ((n0 + nf*16 + lm) < NTOT) {
                    int n = ns[nf];
                    int ox = n % OW; int t2 = n / OW; int oy = t2 % OH; int b = t2 / OH;
                    unsigned off = ((unsigned)(b*HpN + oy)*WpN + (unsigned)ox)*CN + co;
                    ushort4 s; s.x=f2bf(v[0]); s.y=f2bf(v[1]); s.z=f2bf(v[2]); s.w=f2bf(v[3]);
                    *(ushort4*)(Yp + off) = s;
                }
            }
        }
    }
}

// ---------------------------------------------------------------------------
// input build: x (16,3,448,448) f32 -> X1 bf16 [b][y+3][x+3][ci(4)], padded 456x456
// ---------------------------------------------------------------------------
__global__ void x1build(const float* __restrict__ x, ushort* __restrict__ X1) {
    int idx = blockIdx.x*256 + (int)threadIdx.x;      // 16*448*448 exactly
    int xx = idx % 448; int t = idx/448; int y = t % 448; int b = t/448;
    const float* px = x + ((size_t)b*3*448 + y)*448 + xx;
    ushort4 s;
    s.x = f2bf(px[0]); s.y = f2bf(px[200704]); s.z = f2bf(px[401408]); s.w = 0;
    *(ushort4*)(X1 + ((unsigned)(b*456 + y+3)*456 + (unsigned)(xx+3))*4) = s;
}

__global__ void wcvt1(const float* __restrict__ w, ushort* __restrict__ o) {
    int idx = blockIdx.x*256 + (int)threadIdx.x;      // 64*224 = 14336
    if (idx >= 64*224) return;
    int r = idx % 224; int co = idx / 224;
    int ky = r / 32; int t = r % 32; int kx = t / 4; int ci = t % 4;
    float v = 0.f;
    if (kx < 7 && ci < 3) v = w[(((size_t)co*3 + ci)*7 + ky)*7 + kx];
    o[idx] = f2bf(v);
}

template<int CIN,int K>
__global__ void wcvt(const float* __restrict__ w, ushort* __restrict__ o, int total) {
    int idx = blockIdx.x*256 + (int)threadIdx.x;
    if (idx >= total) return;
    int ci = idx % CIN; int t = idx / CIN;
    int kx = t % K; t /= K; int ky = t % K; int co = t / K;
    o[idx] = f2bf(w[(((size_t)co*CIN + ci)*K + ky)*K + kx]);
}

// ---------------------------------------------------------------------------
// maxpool k=5 s=4: XU3 bf16 NHWC (16,10,10,1024) -> pp f32 [b*1024+c][4]
// ---------------------------------------------------------------------------
__global__ void pool54_k(const ushort* __restrict__ in, float* __restrict__ out) {
    int idx = blockIdx.x*256 + (int)threadIdx.x;      // 16*4*1024 = 65536
    int c = idx & 1023; int t = idx >> 10; int q = t & 3; int b = t >> 2;
    int i = q >> 1, j = q & 1;
    float m = -1e30f;
    UNR for (int r=0;r<5;++r)
        UNR for (int cc=0;cc<5;++cc)
            m = fmaxf(m, bf2f(in[(((unsigned)(b*10 + i*4+r))*10 + (unsigned)(j*4+cc))*1024 + c]));
    out[((size_t)(b*1024 + c))*4 + q] = m;
}

// ---------------------------------------------------------------------------
// bilinear 2x2->7x7, pad, im2col:  P[b*1024+c][hw=49][k=9]  (f32)
// ---------------------------------------------------------------------------
__device__ __forceinline__ void bigrid(int k, int& lo, float& f) {
    float c = ((float)k + 0.5f) * (2.0f/7.0f) - 0.5f;
    c = fminf(fmaxf(c, 0.f), 1.f);
    float fl = floorf(c);
    lo = (int)fl;
    f = c - fl;
}

__global__ void buildP_k(const float* __restrict__ pool, float* __restrict__ P) {
    int idx = blockIdx.x*256 + (int)threadIdx.x;   // 7,225,344 exactly
    int k  = idx % 9;
    int r_ = idx / 9;
    int hw = r_ % 49;
    int bc = r_ / 49;
    int i = k/3, j = k%3;
    int h = hw/7, w2 = hw%7;
    int rr = h + i - 1, cc = w2 + j - 1;
    float val = 0.f;
    if (rr>=0 && rr<7 && cc>=0 && cc<7) {
        int rlo; float rf; bigrid(rr, rlo, rf);
        int clo; float cf; bigrid(cc, clo, cf);
        int rhi = min(rlo+1,1), chi = min(clo+1,1);
        const float* q = pool + (size_t)bc*4;
        float v00=q[rlo*2+clo], v01=q[rlo*2+chi], v10=q[rhi*2+clo], v11=q[rhi*2+chi];
        float top = v00*(1.f-cf) + v01*cf;
        float bot = v10*(1.f-cf) + v11*cf;
        val = top*(1.f-rf) + bot*rf;
    }
    P[idx] = val;
}

// ---------------------------------------------------------------------------
// Local conv partials. hw = blockIdx.x (uniform) -> P loads are scalar
// (constant cache, zero vector-L1 transactions). lane = o -> weight reads
// lcw[c][o][hw][0..8]; every fetched line fully consumed across hw-blocks
// via L2/L3 (28.9 MB split working set). Partials stored lane-contiguous.
// ---------------------------------------------------------------------------
__global__ __launch_bounds__(256)
void lconv_k(const float* __restrict__ P, const float* __restrict__ lcw,
             float* __restrict__ part) {
    const int hw = blockIdx.x;        // 0..48
    const int s  = blockIdx.y;        // 0..15
    const int o  = (int)threadIdx.x;  // 0..255
    const int c0 = s*64;
    float acc[16];
    UNR for (int b=0;b<16;++b) acc[b]=0.f;
    const float* wbase = lcw + (size_t)c0*112896 + (size_t)o*441 + hw*9;
    const float* pbase = P   + (size_t)c0*441 + hw*9;
    for (int ci=0; ci<64; ++ci) {
        const float* wp = wbase + (size_t)ci*112896;
        float wv[9];
        UNR for (int k=0;k<9;++k) wv[k]=wp[k];
        const float* pb_ = pbase + (size_t)ci*441;
        UNR for (int b=0;b<16;++b) {
            const float* q = pb_ + (size_t)b*451584;   // b*1024*441
            UNR for (int k=0;k<9;++k) acc[b] = fmaf(q[k], wv[k], acc[b]);
        }
    }
    UNR for (int b=0;b<16;++b)
        part[(((size_t)(s*16+b))*49 + hw)*256 + o] = acc[b];
}

// part [s][b][hw][o] -> yact[b][o*49+hw] with bias + leaky relu
__global__ void lreduce_k(const float* __restrict__ part, const float* __restrict__ lcb,
                          float* __restrict__ yact) {
    int idx = blockIdx.x*256 + (int)threadIdx.x;  // 200704 exactly
    int o = idx & 255; int t = idx >> 8; int hw = t % 49; int b = t / 49;
    float sum = 0.f;
    UNR for (int s=0;s<16;++s) sum += part[(((size_t)(s*16+b))*49 + hw)*256 + o];
    sum += lcb[o*49 + hw];
    float v = (sum > 0.f) ? sum : 0.1f*sum;
    yact[b*12544 + o*49 + hw] = v;
}

// ---------------------------------------------------------------------------
// FC
// ---------------------------------------------------------------------------
__global__ __launch_bounds__(256)
void fc_k(const float* __restrict__ act, const float* __restrict__ fw,
          const float* __restrict__ fb, float* __restrict__ out) {
    __shared__ float alds[16][256];
    __shared__ float red[4][4][16];
    const int t = (int)threadIdx.x;
    const int o0 = blockIdx.x*4;
    float acc[4][16];
    UNR for (int oo=0;oo<4;++oo) UNR for (int b=0;b<16;++b) acc[oo][b]=0.f;

    for (int k0=0; k0<12544; k0+=256) {
        __syncthreads();
        UNR for (int b=0;b<16;++b) alds[b][t] = act[b*12544 + k0 + t];
        __syncthreads();
        float wv[4];
        UNR for (int oo=0;oo<4;++oo) {
            int o = o0+oo;
            wv[oo] = (o < 4949) ? fw[(size_t)o*12544 + k0 + t] : 0.f;
        }
        UNR for (int b=0;b<16;++b) {
            float av = alds[b][t];
            UNR for (int oo=0;oo<4;++oo) acc[oo][b] = fmaf(wv[oo], av, acc[oo][b]);
        }
    }
    UNR for (int oo=0;oo<4;++oo)
        UNR for (int b=0;b<16;++b) {
            float v = acc[oo][b];
            UNR for (int off=32; off; off>>=1) v += __shfl_xor(v, off, 64);
            acc[oo][b] = v;
        }
    const int wave = t>>6, lane = t&63;
    if (lane == 0)
        UNR for (int oo=0;oo<4;++oo)
            UNR for (int b=0;b<16;++b) red[wave][oo][b] = acc[oo][b];
    __syncthreads();
    if (t < 64) {
        int oo = t>>4, b = t&15;
        float v = red[0][oo][b]+red[1][oo][b]+red[2][oo][b]+red[3][oo][b];
        int o = o0+oo;
        if (o < 4949) out[b*4949 + o] = v + fb[o];
    }
}

// ---------------------------------------------------------------------------
extern "C" void kernel_launch(void* const* d_in, const int* in_sizes, int n_in,
                              void* d_out, int out_size, void* d_ws, size_t ws_size,
                              hipStream_t stream) {
    const float* x   = (const float*)d_in[0];
    const float* w1  = (const float*)d_in[1];
    const float* b1  = (const float*)d_in[2];
    const float* w3  = (const float*)d_in[3];
    const float* b3  = (const float*)d_in[4];
    const float* w4  = (const float*)d_in[5];
    const float* b4  = (const float*)d_in[6];
    const float* w7  = (const float*)d_in[7];
    const float* b7  = (const float*)d_in[8];
    const float* w8  = (const float*)d_in[9];
    const float* b8  = (const float*)d_in[10];
    const float* wu  = (const float*)d_in[11];
    const float* bu  = (const float*)d_in[12];
    const float* lcw = (const float*)d_in[13];
    const float* lcb = (const float*)d_in[14];
    const float* fw  = (const float*)d_in[15];
    const float* fb  = (const float*)d_in[16];
    float* out = (float*)d_out;

    // --- workspace carve (bytes, 256-aligned) ---
    char* base = (char*)d_ws;
    auto alloc = [&](size_t bytes) { char* p = base; base += (bytes + 255) & ~(size_t)255; return p; };
    ushort* X1  = (ushort*)alloc(16u*456*456*4*2);   // 26.6 MB (later reused as P)
    ushort* X3  = (ushort*)alloc(16u*114*114*64*2);  // 26.6 MB
    ushort* X4  = (ushort*)alloc(16u*56*56*192*2);   // 19.3 MB (later reused as part)
    ushort* X7  = (ushort*)alloc(16u*27*27*256*2);   // 6.0 MB (later reused as yact)
    ushort* X8  = (ushort*)alloc(16u*13*13*512*2);
    ushort* XU1 = (ushort*)alloc(16u*12*12*1024*2);
    ushort* XU2 = (ushort*)alloc(16u*11*11*1024*2);
    ushort* XU3 = (ushort*)alloc(16u*10*10*1024*2);
    ushort* W1b = (ushort*)alloc(64u*224*2);
    ushort* W3b = (ushort*)alloc(192u*576*2);
    ushort* W4b = (ushort*)alloc(256u*1728*2);
    ushort* W7b = (ushort*)alloc(512u*1024*2);
    ushort* W8b = (ushort*)alloc(1024u*2048*2);
    ushort* WUb = (ushort*)alloc(1024u*4096*2);
    float*  pp  = (float*)alloc(16u*1024*4*4);
    // aliased (lifetimes disjoint):
    float*  P    = (float*)X1;   // 28.9 MB over X1+X3 (both dead by then)
    float*  part = (float*)X4;   // 12.8 MB over X4 (dead)
    float*  yact = (float*)X7;   // 0.8 MB over X7 (dead)

    // --- prep ---
    hipMemsetAsync(X1, 0, 16u*456*456*4*2, stream);
    hipMemsetAsync(X3, 0, 16u*114*114*64*2, stream);
    x1build<<<12544, 256, 0, stream>>>(x, X1);
    wcvt1<<<56, 256, 0, stream>>>(w1, W1b);
    wcvt<64,3><<<432, 256, 0, stream>>>(w3, W3b, 192*576);
    wcvt<192,3><<<1728, 256, 0, stream>>>(w4, W4b, 256*1728);
    wcvt<256,2><<<2048, 256, 0, stream>>>(w7, W7b, 512*1024);
    wcvt<512,2><<<8192, 256, 0, stream>>>(w8, W8b, 1024*2048);
    wcvt<1024,2><<<16384, 256, 0, stream>>>(wu, WUb, 1024*4096);

    // --- conv chain (MFMA, fused pool) ---
    convmf<4,7,2,456,456,224,224,64, true,114,114,1,64, 4,true>
        <<<dim3(3136,1), 256, 0, stream>>>(X1, W1b, b1, X3);
    convmf<64,3,1,114,114,112,112,192, true,56,56,0,192, 4,false>
        <<<dim3(784,3), 256, 0, stream>>>(X3, W3b, b3, X4);
    convmf<192,3,1,56,56,54,54,256, true,27,27,0,256, 4,false>
        <<<dim3(183,4), 256, 0, stream>>>(X4, W4b, b4, X7);
    convmf<256,2,1,27,27,26,26,512, true,13,13,0,512, 1,false>
        <<<dim3(169,8), 64, 0, stream>>>(X7, W7b, b7, X8);
    convmf<512,2,1,13,13,12,12,1024, false,12,12,0,1024, 1,false>
        <<<dim3(36,16), 64, 0, stream>>>(X8, W8b, b8, XU1);
    convmf<1024,2,1,12,12,11,11,1024, false,11,11,0,1024, 1,false>
        <<<dim3(31,16), 64, 0, stream>>>(XU1, WUb, bu, XU2);
    convmf<1024,2,1,11,11,10,10,1024, false,10,10,0,1024, 1,false>
        <<<dim3(25,16), 64, 0, stream>>>(XU2, WUb, bu, XU3);

    // --- head (fp32) ---
    pool54_k<<<256, 256, 0, stream>>>(XU3, pp);
    buildP_k<<<28224, 256, 0, stream>>>(pp, P);
    lconv_k<<<dim3(49,16), 256, 0, stream>>>(P, lcw, part);
    lreduce_k<<<784, 256, 0, stream>>>(part, lcb, yact);
    fc_k<<<1238, 256, 0, stream>>>(yact, fw, fb, out);
}

// Round 4
// 1241.496 us; speedup vs baseline: 3.2413x; 1.0559x over previous
//
#include <hip/hip_runtime.h>

#define UNR _Pragma("unroll")

typedef __attribute__((ext_vector_type(8))) short short8v;
typedef __attribute__((ext_vector_type(4))) float f32x4;

__device__ __forceinline__ ushort f2bf(float f) {
    union { float f; unsigned u; } x; x.f = f;
    unsigned r = (x.u + 0x7fffu + ((x.u >> 16) & 1u)) >> 16;
    return (ushort)r;
}
__device__ __forceinline__ float bf2f(ushort u) {
    union { unsigned u; float f; } x; x.u = ((unsigned)u) << 16;
    return x.f;
}

// ---------------------------------------------------------------------------
// MFMA implicit-GEMM conv, NHWC bf16 activations, fused 2x2/s2 maxpool.
// ---------------------------------------------------------------------------
template<int CIN,int K,int STRIDE,int Wp,int Hp,int OW,int OH,int COUT,
         bool POOL,int WpN,int HpN,int PADN,int CN,int WAVES,bool CI4>
__global__ __launch_bounds__(WAVES*64)
void convmf(const ushort* __restrict__ Xp, const ushort* __restrict__ Wb,
            const float* __restrict__ bias, ushort* __restrict__ Yp)
{
    constexpr int KK   = CI4 ? 224 : K*K*CIN;
    constexpr int POW  = OW/2, POH = OH/2;
    constexpr int NTOT = POOL ? 16*POW*POH*4 : 16*OW*OH;

    const int lane = (int)threadIdx.x & 63;
    const int wave = (int)threadIdx.x >> 6;
    const int n0   = (blockIdx.x*WAVES + wave) * 64;
    const int co0  = blockIdx.y * 64;
    const int lm   = lane & 15;   // A-row / B-col / D-col
    const int lk   = lane >> 4;   // k-group

    unsigned boff[4];
    int ns[4];
    UNR for (int nf=0; nf<4; ++nf) {
        int n = n0 + nf*16 + lm;
        if (n > NTOT-1) n = NTOT-1;
        ns[nf] = n;
        int b, oy, ox;
        if constexpr (POOL) {
            int q = n & 3, pp = n >> 2;
            int px = pp % POW; int t = pp / POW;
            int py = t % POH;  b = t / POH;
            oy = 2*py + (q>>1); ox = 2*px + (q&1);
        } else {
            ox = n % OW; int t = n / OW; oy = t % OH; b = t / OH;
        }
        boff[nf] = ((unsigned)(b*Hp + oy*STRIDE)*Wp + (unsigned)(ox*STRIDE))*CIN
                 + 8u*lk;
    }
    const unsigned abase = (unsigned)(co0 + lm)*KK + 8u*lk;

    f32x4 acc[4][4];
    UNR for (int i=0;i<4;++i) UNR for (int j=0;j<4;++j) acc[i][j] = f32x4{0.f,0.f,0.f,0.f};

    auto step = [&](unsigned aoff, unsigned xoff) {
        short8v a[4], bf[4];
        UNR for (int mf=0; mf<4; ++mf)
            a[mf] = *(const short8v*)(Wb + abase + aoff + (unsigned)mf*16u*KK);
        UNR for (int nf=0; nf<4; ++nf)
            bf[nf] = *(const short8v*)(Xp + boff[nf] + xoff);
        UNR for (int mf=0; mf<4; ++mf)
            UNR for (int nf=0; nf<4; ++nf)
                acc[mf][nf] = __builtin_amdgcn_mfma_f32_16x16x32_bf16(
                                  a[mf], bf[nf], acc[mf][nf], 0, 0, 0);
    };

    if constexpr (CI4) {
        UNR for (int ky=0; ky<7; ++ky)
            step((unsigned)(ky*32), (unsigned)(ky*Wp)*4u);
    } else {
        UNR for (int ky=0; ky<K; ++ky)
            UNR for (int kx=0; kx<K; ++kx)
                for (int c0=0; c0<CIN; c0+=32)
                    step((unsigned)((ky*K+kx)*CIN + c0),
                         (unsigned)((ky*Wp+kx)*CIN + c0));
    }

    UNR for (int mf=0; mf<4; ++mf) {
        const int co = co0 + mf*16 + 4*lk;
        f32x4 bi = *(const f32x4*)(bias + co);
        UNR for (int nf=0; nf<4; ++nf) {
            f32x4 v = acc[mf][nf];
            UNR for (int r=0;r<4;++r) v[r] += bi[r];
            if constexpr (POOL) {
                UNR for (int r=0;r<4;++r) {
                    float t = v[r];
                    t = fmaxf(t, __shfl_xor(t, 1, 64));
                    t = fmaxf(t, __shfl_xor(t, 2, 64));
                    v[r] = t;
                }
                if ((lane & 3) == 0 && (n0 + nf*16 + lm) < NTOT) {
                    int pp = ns[nf] >> 2;
                    int px = pp % POW; int t2 = pp / POW;
                    int py = t2 % POH; int b = t2 / POH;
                    unsigned off = ((unsigned)(b*HpN + py + PADN)*WpN
                                    + (unsigned)(px + PADN))*CN + co;
                    ushort4 s; s.x=f2bf(v[0]); s.y=f2bf(v[1]); s.z=f2bf(v[2]); s.w=f2bf(v[3]);
                    *(ushort4*)(Yp + off) = s;
                }
            } else {
                if ((n0 + nf*16 + lm) < NTOT) {
                    int n = ns[nf];
                    int ox = n % OW; int t2 = n / OW; int oy = t2 % OH; int b = t2 / OH;
                    unsigned off = ((unsigned)(b*HpN + oy)*WpN + (unsigned)ox)*CN + co;
                    ushort4 s; s.x=f2bf(v[0]); s.y=f2bf(v[1]); s.z=f2bf(v[2]); s.w=f2bf(v[3]);
                    *(ushort4*)(Yp + off) = s;
                }
            }
        }
    }
}

// ---------------------------------------------------------------------------
// input build: x (16,3,448,448) f32 -> X1 bf16 [b][y+3][x+3][ci(4)], padded 456x456
// ---------------------------------------------------------------------------
__global__ void x1build(const float* __restrict__ x, ushort* __restrict__ X1) {
    int idx = blockIdx.x*256 + (int)threadIdx.x;      // 16*448*448 exactly
    int xx = idx % 448; int t = idx/448; int y = t % 448; int b = t/448;
    const float* px = x + ((size_t)b*3*448 + y)*448 + xx;
    ushort4 s;
    s.x = f2bf(px[0]); s.y = f2bf(px[200704]); s.z = f2bf(px[401408]); s.w = 0;
    *(ushort4*)(X1 + ((unsigned)(b*456 + y+3)*456 + (unsigned)(xx+3))*4) = s;
}

__global__ void wcvt1(const float* __restrict__ w, ushort* __restrict__ o) {
    int idx = blockIdx.x*256 + (int)threadIdx.x;      // 64*224 = 14336
    if (idx >= 64*224) return;
    int r = idx % 224; int co = idx / 224;
    int ky = r / 32; int t = r % 32; int kx = t / 4; int ci = t % 4;
    float v = 0.f;
    if (kx < 7 && ci < 3) v = w[(((size_t)co*3 + ci)*7 + ky)*7 + kx];
    o[idx] = f2bf(v);
}

template<int CIN,int K>
__global__ void wcvt(const float* __restrict__ w, ushort* __restrict__ o, int total) {
    int idx = blockIdx.x*256 + (int)threadIdx.x;
    if (idx >= total) return;
    int ci = idx % CIN; int t = idx / CIN;
    int kx = t % K; t /= K; int ky = t % K; int co = t / K;
    o[idx] = f2bf(w[(((size_t)co*CIN + ci)*K + ky)*K + kx]);
}

// ---------------------------------------------------------------------------
// maxpool k=5 s=4: XU3 bf16 NHWC (16,10,10,1024) -> pp f32 [b*1024+c][4]
// ---------------------------------------------------------------------------
__global__ void pool54_k(const ushort* __restrict__ in, float* __restrict__ out) {
    int idx = blockIdx.x*256 + (int)threadIdx.x;      // 16*4*1024 = 65536
    int c = idx & 1023; int t = idx >> 10; int q = t & 3; int b = t >> 2;
    int i = q >> 1, j = q & 1;
    float m = -1e30f;
    UNR for (int r=0;r<5;++r)
        UNR for (int cc=0;cc<5;++cc)
            m = fmaxf(m, bf2f(in[(((unsigned)(b*10 + i*4+r))*10 + (unsigned)(j*4+cc))*1024 + c]));
    out[((size_t)(b*1024 + c))*4 + q] = m;
}

// ---------------------------------------------------------------------------
// bilinear 2x2->7x7, pad, im2col:  P[b*1024+c][hw=49][k=9]  (f32)
// ---------------------------------------------------------------------------
__device__ __forceinline__ void bigrid(int k, int& lo, float& f) {
    float c = ((float)k + 0.5f) * (2.0f/7.0f) - 0.5f;
    c = fminf(fmaxf(c, 0.f), 1.f);
    float fl = floorf(c);
    lo = (int)fl;
    f = c - fl;
}

__global__ void buildP_k(const float* __restrict__ pool, float* __restrict__ P) {
    int idx = blockIdx.x*256 + (int)threadIdx.x;   // 7,225,344 exactly
    int k  = idx % 9;
    int r_ = idx / 9;
    int hw = r_ % 49;
    int bc = r_ / 49;
    int i = k/3, j = k%3;
    int h = hw/7, w2 = hw%7;
    int rr = h + i - 1, cc = w2 + j - 1;
    float val = 0.f;
    if (rr>=0 && rr<7 && cc>=0 && cc<7) {
        int rlo; float rf; bigrid(rr, rlo, rf);
        int clo; float cf; bigrid(cc, clo, cf);
        int rhi = min(rlo+1,1), chi = min(clo+1,1);
        const float* q = pool + (size_t)bc*4;
        float v00=q[rlo*2+clo], v01=q[rlo*2+chi], v10=q[rhi*2+clo], v11=q[rhi*2+chi];
        float top = v00*(1.f-cf) + v01*cf;
        float bot = v10*(1.f-cf) + v11*cf;
        val = top*(1.f-rf) + bot*rf;
    }
    P[idx] = val;
}

// ---------------------------------------------------------------------------
// Local conv partials. hw uniform per block (P loads scalar), lane = o.
// XCD-pinned remap: all 49 hw-blocks of a split s land on one XCD (assuming
// HW round-robin xcd = linear_wgid % 8), so L2 serves the line-sharing
// between adjacent 36B hw-segments of each 1764B weight row (~3.5 hw / line).
// ---------------------------------------------------------------------------
__global__ __launch_bounds__(256)
void lconv_k(const float* __restrict__ P, const float* __restrict__ lcw,
             float* __restrict__ part) {
    const int bid = (int)blockIdx.x;      // 0..783
    const int xcd = bid & 7;
    const int idx = bid >> 3;             // 0..97
    const int s   = xcd + 8*(idx/49);     // split 0..15, pinned to xcd
    const int hw  = idx % 49;             // 0..48
    const int o   = (int)threadIdx.x;     // 0..255
    const int c0  = s*64;
    float acc[16];
    UNR for (int b=0;b<16;++b) acc[b]=0.f;
    const float* wbase = lcw + (size_t)c0*112896 + (size_t)o*441 + hw*9;
    const float* pbase = P   + (size_t)c0*441 + hw*9;
    for (int ci=0; ci<64; ++ci) {
        const float* wp = wbase + (size_t)ci*112896;
        float wv[9];
        UNR for (int k=0;k<9;++k) wv[k]=wp[k];
        const float* pb_ = pbase + (size_t)ci*441;
        UNR for (int b=0;b<16;++b) {
            const float* q = pb_ + (size_t)b*451584;   // b*1024*441
            UNR for (int k=0;k<9;++k) acc[b] = fmaf(q[k], wv[k], acc[b]);
        }
    }
    UNR for (int b=0;b<16;++b)
        part[(((size_t)(s*16+b))*49 + hw)*256 + o] = acc[b];
}

// part [s][b][hw][o] -> yact[b][o*49+hw] with bias + leaky relu
__global__ void lreduce_k(const float* __restrict__ part, const float* __restrict__ lcb,
                          float* __restrict__ yact) {
    int idx = blockIdx.x*256 + (int)threadIdx.x;  // 200704 exactly
    int o = idx & 255; int t = idx >> 8; int hw = t % 49; int b = t / 49;
    float sum = 0.f;
    UNR for (int s=0;s<16;++s) sum += part[(((size_t)(s*16+b))*49 + hw)*256 + o];
    sum += lcb[o*49 + hw];
    float v = (sum > 0.f) ? sum : 0.1f*sum;
    yact[b*12544 + o*49 + hw] = v;
}

// ---------------------------------------------------------------------------
// FC
// ---------------------------------------------------------------------------
__global__ __launch_bounds__(256)
void fc_k(const float* __restrict__ act, const float* __restrict__ fw,
          const float* __restrict__ fb, float* __restrict__ out) {
    __shared__ float alds[16][256];
    __shared__ float red[4][4][16];
    const int t = (int)threadIdx.x;
    const int o0 = blockIdx.x*4;
    float acc[4][16];
    UNR for (int oo=0;oo<4;++oo) UNR for (int b=0;b<16;++b) acc[oo][b]=0.f;

    for (int k0=0; k0<12544; k0+=256) {
        __syncthreads();
        UNR for (int b=0;b<16;++b) alds[b][t] = act[b*12544 + k0 + t];
        __syncthreads();
        float wv[4];
        UNR for (int oo=0;oo<4;++oo) {
            int o = o0+oo;
            wv[oo] = (o < 4949) ? fw[(size_t)o*12544 + k0 + t] : 0.f;
        }
        UNR for (int b=0;b<16;++b) {
            float av = alds[b][t];
            UNR for (int oo=0;oo<4;++oo) acc[oo][b] = fmaf(wv[oo], av, acc[oo][b]);
        }
    }
    UNR for (int oo=0;oo<4;++oo)
        UNR for (int b=0;b<16;++b) {
            float v = acc[oo][b];
            UNR for (int off=32; off; off>>=1) v += __shfl_xor(v, off, 64);
            acc[oo][b] = v;
        }
    const int wave = t>>6, lane = t&63;
    if (lane == 0)
        UNR for (int oo=0;oo<4;++oo)
            UNR for (int b=0;b<16;++b) red[wave][oo][b] = acc[oo][b];
    __syncthreads();
    if (t < 64) {
        int oo = t>>4, b = t&15;
        float v = red[0][oo][b]+red[1][oo][b]+red[2][oo][b]+red[3][oo][b];
        int o = o0+oo;
        if (o < 4949) out[b*4949 + o] = v + fb[o];
    }
}

// ---------------------------------------------------------------------------
extern "C" void kernel_launch(void* const* d_in, const int* in_sizes, int n_in,
                              void* d_out, int out_size, void* d_ws, size_t ws_size,
                              hipStream_t stream) {
    const float* x   = (const float*)d_in[0];
    const float* w1  = (const float*)d_in[1];
    const float* b1  = (const float*)d_in[2];
    const float* w3  = (const float*)d_in[3];
    const float* b3  = (const float*)d_in[4];
    const float* w4  = (const float*)d_in[5];
    const float* b4  = (const float*)d_in[6];
    const float* w7  = (const float*)d_in[7];
    const float* b7  = (const float*)d_in[8];
    const float* w8  = (const float*)d_in[9];
    const float* b8  = (const float*)d_in[10];
    const float* wu  = (const float*)d_in[11];
    const float* bu  = (const float*)d_in[12];
    const float* lcw = (const float*)d_in[13];
    const float* lcb = (const float*)d_in[14];
    const float* fw  = (const float*)d_in[15];
    const float* fb  = (const float*)d_in[16];
    float* out = (float*)d_out;

    // --- workspace carve (bytes, 256-aligned) ---
    char* base = (char*)d_ws;
    auto alloc = [&](size_t bytes) { char* p = base; base += (bytes + 255) & ~(size_t)255; return p; };
    ushort* X1  = (ushort*)alloc(16u*456*456*4*2);   // 26.6 MB (later reused as P)
    ushort* X3  = (ushort*)alloc(16u*114*114*64*2);  // 26.6 MB
    ushort* X4  = (ushort*)alloc(16u*56*56*192*2);   // 19.3 MB (later reused as part)
    ushort* X7  = (ushort*)alloc(16u*27*27*256*2);   // 6.0 MB (later reused as yact)
    ushort* X8  = (ushort*)alloc(16u*13*13*512*2);
    ushort* XU1 = (ushort*)alloc(16u*12*12*1024*2);
    ushort* XU2 = (ushort*)alloc(16u*11*11*1024*2);
    ushort* XU3 = (ushort*)alloc(16u*10*10*1024*2);
    ushort* W1b = (ushort*)alloc(64u*224*2);
    ushort* W3b = (ushort*)alloc(192u*576*2);
    ushort* W4b = (ushort*)alloc(256u*1728*2);
    ushort* W7b = (ushort*)alloc(512u*1024*2);
    ushort* W8b = (ushort*)alloc(1024u*2048*2);
    ushort* WUb = (ushort*)alloc(1024u*4096*2);
    float*  pp  = (float*)alloc(16u*1024*4*4);
    // aliased (lifetimes disjoint):
    float*  P    = (float*)X1;   // 28.9 MB over X1+X3 (both dead by then)
    float*  part = (float*)X4;   // 12.8 MB over X4 (dead)
    float*  yact = (float*)X7;   // 0.8 MB over X7 (dead)

    // --- prep ---
    hipMemsetAsync(X1, 0, 16u*456*456*4*2, stream);
    hipMemsetAsync(X3, 0, 16u*114*114*64*2, stream);
    x1build<<<12544, 256, 0, stream>>>(x, X1);
    wcvt1<<<56, 256, 0, stream>>>(w1, W1b);
    wcvt<64,3><<<432, 256, 0, stream>>>(w3, W3b, 192*576);
    wcvt<192,3><<<1728, 256, 0, stream>>>(w4, W4b, 256*1728);
    wcvt<256,2><<<2048, 256, 0, stream>>>(w7, W7b, 512*1024);
    wcvt<512,2><<<8192, 256, 0, stream>>>(w8, W8b, 1024*2048);
    wcvt<1024,2><<<16384, 256, 0, stream>>>(wu, WUb, 1024*4096);

    // --- conv chain (MFMA, fused pool) ---
    convmf<4,7,2,456,456,224,224,64, true,114,114,1,64, 4,true>
        <<<dim3(3136,1), 256, 0, stream>>>(X1, W1b, b1, X3);
    convmf<64,3,1,114,114,112,112,192, true,56,56,0,192, 4,false>
        <<<dim3(784,3), 256, 0, stream>>>(X3, W3b, b3, X4);
    convmf<192,3,1,56,56,54,54,256, true,27,27,0,256, 4,false>
        <<<dim3(183,4), 256, 0, stream>>>(X4, W4b, b4, X7);
    convmf<256,2,1,27,27,26,26,512, true,13,13,0,512, 1,false>
        <<<dim3(169,8), 64, 0, stream>>>(X7, W7b, b7, X8);
    convmf<512,2,1,13,13,12,12,1024, false,12,12,0,1024, 1,false>
        <<<dim3(36,16), 64, 0, stream>>>(X8, W8b, b8, XU1);
    convmf<1024,2,1,12,12,11,11,1024, false,11,11,0,1024, 1,false>
        <<<dim3(31,16), 64, 0, stream>>>(XU1, WUb, bu, XU2);
    convmf<1024,2,1,11,11,10,10,1024, false,10,10,0,1024, 1,false>
        <<<dim3(25,16), 64, 0, stream>>>(XU2, WUb, bu, XU3);

    // --- head (fp32) ---
    pool54_k<<<256, 256, 0, stream>>>(XU3, pp);
    buildP_k<<<28224, 256, 0, stream>>>(pp, P);
    lconv_k<<<784, 256, 0, stream>>>(P, lcw, part);
    lreduce_k<<<784, 256, 0, stream>>>(part, lcb, yact);
    fc_k<<<1238, 256, 0, stream>>>(yact, fw, fb, out);
}

// Round 6
// 1109.984 us; speedup vs baseline: 3.6254x; 1.1185x over previous
//
#include <hip/hip_runtime.h>

#define UNR _Pragma("unroll")

typedef __attribute__((ext_vector_type(8))) short short8v;
typedef __attribute__((ext_vector_type(4))) float f32x4;

__device__ __forceinline__ ushort f2bf(float f) {
    union { float f; unsigned u; } x; x.f = f;
    unsigned r = (x.u + 0x7fffu + ((x.u >> 16) & 1u)) >> 16;
    return (ushort)r;
}
__device__ __forceinline__ float bf2f(ushort u) {
    union { unsigned u; float f; } x; x.u = ((unsigned)u) << 16;
    return x.f;
}

// ---------------------------------------------------------------------------
// MFMA implicit-GEMM conv, NHWC bf16, fused 2x2/s2 maxpool.
// K-loop flattened to steps; A/B fragments register-double-buffered so the
// next step's 8 gather loads are in flight during the current 16 MFMAs.
// ---------------------------------------------------------------------------
template<int CIN,int K,int STRIDE,int Wp,int Hp,int OW,int OH,int COUT,
         bool POOL,int WpN,int HpN,int PADN,int CN,int WAVES,bool CI4>
__global__ __launch_bounds__(WAVES*64)
void convmf(const ushort* __restrict__ Xp, const ushort* __restrict__ Wb,
            const float* __restrict__ bias, ushort* __restrict__ Yp)
{
    constexpr int KK    = CI4 ? 224 : K*K*CIN;
    constexpr int POW   = OW/2, POH = OH/2;
    constexpr int NTOT  = POOL ? 16*POW*POH*4 : 16*OW*OH;
    constexpr int NCH   = CI4 ? 1 : CIN/32;
    constexpr int NSTEP = CI4 ? 7 : K*K*NCH;

    const int lane = (int)threadIdx.x & 63;
    const int wave = (int)threadIdx.x >> 6;
    const int n0   = (blockIdx.x*WAVES + wave) * 64;
    const int co0  = blockIdx.y * 64;
    const int lm   = lane & 15;   // A-row / B-col / D-col
    const int lk   = lane >> 4;   // k-group

    unsigned boff[4];
    int ns[4];
    UNR for (int nf=0; nf<4; ++nf) {
        int n = n0 + nf*16 + lm;
        if (n > NTOT-1) n = NTOT-1;
        ns[nf] = n;
        int b, oy, ox;
        if constexpr (POOL) {
            int q = n & 3, pp = n >> 2;
            int px = pp % POW; int t = pp / POW;
            int py = t % POH;  b = t / POH;
            oy = 2*py + (q>>1); ox = 2*px + (q&1);
        } else {
            ox = n % OW; int t = n / OW; oy = t % OH; b = t / OH;
        }
        boff[nf] = ((unsigned)(b*Hp + oy*STRIDE)*Wp + (unsigned)(ox*STRIDE))*CIN
                 + 8u*lk;
    }
    const unsigned abase = (unsigned)(co0 + lm)*KK + 8u*lk;

    f32x4 acc[4][4];
    UNR for (int i=0;i<4;++i) UNR for (int j=0;j<4;++j) acc[i][j] = f32x4{0.f,0.f,0.f,0.f};

    // step s -> (aoff, xoff); wave-uniform SALU arithmetic
    auto offs = [&](int s, unsigned& aoff, unsigned& xoff) {
        if constexpr (CI4) {
            aoff = (unsigned)(s*32);
            xoff = (unsigned)(s*Wp*CIN);
        } else {
            int c0  = (s % NCH)*32;
            int kxy = s / NCH;
            int kx  = kxy % K, ky = kxy / K;
            aoff = (unsigned)(kxy*CIN + c0);
            xoff = (unsigned)((ky*Wp + kx)*CIN + c0);
        }
    };
    auto ldfr = [&](int s, short8v (&a)[4], short8v (&bf)[4]) {
        unsigned aoff, xoff; offs(s, aoff, xoff);
        UNR for (int mf=0; mf<4; ++mf)
            a[mf] = *(const short8v*)(Wb + abase + aoff + (unsigned)mf*16u*KK);
        UNR for (int nf=0; nf<4; ++nf)
            bf[nf] = *(const short8v*)(Xp + boff[nf] + xoff);
    };
    auto dm = [&](short8v (&a)[4], short8v (&bf)[4]) {
        UNR for (int mf=0; mf<4; ++mf)
            UNR for (int nf=0; nf<4; ++nf)
                acc[mf][nf] = __builtin_amdgcn_mfma_f32_16x16x32_bf16(
                                  a[mf], bf[nf], acc[mf][nf], 0, 0, 0);
    };

    short8v aA[4], bA[4], aB[4], bB[4];
    ldfr(0, aA, bA);
    for (int sb = 0; sb < NSTEP; sb += 2) {
        if (sb+1 < NSTEP) ldfr(sb+1, aB, bB);
        dm(aA, bA);
        if (sb+2 < NSTEP) ldfr(sb+2, aA, bA);
        if (sb+1 < NSTEP) dm(aB, bB);
    }

    UNR for (int mf=0; mf<4; ++mf) {
        const int co = co0 + mf*16 + 4*lk;
        f32x4 bi = *(const f32x4*)(bias + co);
        UNR for (int nf=0; nf<4; ++nf) {
            f32x4 v = acc[mf][nf];
            UNR for (int r=0;r<4;++r) v[r] += bi[r];
            if constexpr (POOL) {
                UNR for (int r=0;r<4;++r) {
                    float t = v[r];
                    t = fmaxf(t, __shfl_xor(t, 1, 64));
                    t = fmaxf(t, __shfl_xor(t, 2, 64));
                    v[r] = t;
                }
                if ((lane & 3) == 0 && (n0 + nf*16 + lm) < NTOT) {
                    int pp = ns[nf] >> 2;
                    int px = pp % POW; int t2 = pp / POW;
                    int py = t2 % POH; int b = t2 / POH;
                    unsigned off = ((unsigned)(b*HpN + py + PADN)*WpN
                                    + (unsigned)(px + PADN))*CN + co;
                    ushort4 s; s.x=f2bf(v[0]); s.y=f2bf(v[1]); s.z=f2bf(v[2]); s.w=f2bf(v[3]);
                    *(ushort4*)(Yp + off) = s;
                }
            } else {
                if ((n0 + nf*16 + lm) < NTOT) {
                    int n = ns[nf];
                    int ox = n % OW; int t2 = n / OW; int oy = t2 % OH; int b = t2 / OH;
                    unsigned off = ((unsigned)(b*HpN + oy)*WpN + (unsigned)ox)*CN + co;
                    ushort4 s; s.x=f2bf(v[0]); s.y=f2bf(v[1]); s.z=f2bf(v[2]); s.w=f2bf(v[3]);
                    *(ushort4*)(Yp + off) = s;
                }
            }
        }
    }
}

// ---------------------------------------------------------------------------
// input build: x (16,3,448,448) f32 -> X1 bf16 [b][y+3][x+3][ci(4)], padded 456x456
// ---------------------------------------------------------------------------
__global__ void x1build(const float* __restrict__ x, ushort* __restrict__ X1) {
    int idx = blockIdx.x*256 + (int)threadIdx.x;      // 16*448*448 exactly
    int xx = idx % 448; int t = idx/448; int y = t % 448; int b = t/448;
    const float* px = x + ((size_t)b*3*448 + y)*448 + xx;
    ushort4 s;
    s.x = f2bf(px[0]); s.y = f2bf(px[200704]); s.z = f2bf(px[401408]); s.w = 0;
    *(ushort4*)(X1 + ((unsigned)(b*456 + y+3)*456 + (unsigned)(xx+3))*4) = s;
}

__global__ void wcvt1(const float* __restrict__ w, ushort* __restrict__ o) {
    int idx = blockIdx.x*256 + (int)threadIdx.x;      // 64*224 = 14336
    if (idx >= 64*224) return;
    int r = idx % 224; int co = idx / 224;
    int ky = r / 32; int t = r % 32; int kx = t / 4; int ci = t % 4;
    float v = 0.f;
    if (kx < 7 && ci < 3) v = w[(((size_t)co*3 + ci)*7 + ky)*7 + kx];
    o[idx] = f2bf(v);
}

template<int CIN,int K>
__global__ void wcvt(const float* __restrict__ w, ushort* __restrict__ o, int total) {
    int idx = blockIdx.x*256 + (int)threadIdx.x;
    if (idx >= total) return;
    int ci = idx % CIN; int t = idx / CIN;
    int kx = t % K; t /= K; int ky = t % K; int co = t / K;
    o[idx] = f2bf(w[(((size_t)co*CIN + ci)*K + ky)*K + kx]);
}

// ---------------------------------------------------------------------------
// maxpool k=5 s=4: XU3 bf16 NHWC (16,10,10,1024) -> pp f32 [b*1024+c][4]
// ---------------------------------------------------------------------------
__global__ void pool54_k(const ushort* __restrict__ in, float* __restrict__ out) {
    int idx = blockIdx.x*256 + (int)threadIdx.x;      // 16*4*1024 = 65536
    int c = idx & 1023; int t = idx >> 10; int q = t & 3; int b = t >> 2;
    int i = q >> 1, j = q & 1;
    float m = -1e30f;
    UNR for (int r=0;r<5;++r)
        UNR for (int cc=0;cc<5;++cc)
            m = fmaxf(m, bf2f(in[(((unsigned)(b*10 + i*4+r))*10 + (unsigned)(j*4+cc))*1024 + c]));
    out[((size_t)(b*1024 + c))*4 + q] = m;
}

// ---------------------------------------------------------------------------
// bilinear 2x2->7x7, pad, im2col:  P[b*1024+c][hw=49][k=9]  (f32)
// ---------------------------------------------------------------------------
__device__ __forceinline__ void bigrid(int k, int& lo, float& f) {
    float c = ((float)k + 0.5f) * (2.0f/7.0f) - 0.5f;
    c = fminf(fmaxf(c, 0.f), 1.f);
    float fl = floorf(c);
    lo = (int)fl;
    f = c - fl;
}

__global__ void buildP_k(const float* __restrict__ pool, float* __restrict__ P) {
    int idx = blockIdx.x*256 + (int)threadIdx.x;   // 7,225,344 exactly
    int k  = idx % 9;
    int r_ = idx / 9;
    int hw = r_ % 49;
    int bc = r_ / 49;
    int i = k/3, j = k%3;
    int h = hw/7, w2 = hw%7;
    int rr = h + i - 1, cc = w2 + j - 1;
    float val = 0.f;
    if (rr>=0 && rr<7 && cc>=0 && cc<7) {
        int rlo; float rf; bigrid(rr, rlo, rf);
        int clo; float cf; bigrid(cc, clo, cf);
        int rhi = min(rlo+1,1), chi = min(clo+1,1);
        const float* q = pool + (size_t)bc*4;
        float v00=q[rlo*2+clo], v01=q[rlo*2+chi], v10=q[rhi*2+clo], v11=q[rhi*2+chi];
        float top = v00*(1.f-cf) + v01*cf;
        float bot = v10*(1.f-cf) + v11*cf;
        val = top*(1.f-rf) + bot*rf;
    }
    P[idx] = val;
}

// ---------------------------------------------------------------------------
// Local conv partials. hw uniform per block (P loads scalar), lane = o.
// XCD-pinned split mapping. Weight loads via 36B memcpy (legal vectorized
// lowering at 4B alignment) and prefetched one c ahead.
// ---------------------------------------------------------------------------
__global__ __launch_bounds__(256)
void lconv_k(const float* __restrict__ P, const float* __restrict__ lcw,
             float* __restrict__ part) {
    const int bid = (int)blockIdx.x;      // 0..783
    const int xcd = bid & 7;
    const int idx = bid >> 3;             // 0..97
    const int s   = xcd + 8*(idx/49);     // split 0..15, pinned to xcd
    const int hw  = idx % 49;             // 0..48
    const int o   = (int)threadIdx.x;     // 0..255
    const int c0  = s*64;
    float acc[16];
    UNR for (int b=0;b<16;++b) acc[b]=0.f;
    const float* wbase = lcw + (size_t)c0*112896 + (size_t)o*441 + hw*9;
    const float* pbase = P   + (size_t)c0*441 + hw*9;

    float wv[9], nv[9];
    __builtin_memcpy(wv, wbase, 36);
    for (int ci=0; ci<64; ++ci) {
        const float* wn = wbase + (size_t)((ci+1 < 64) ? ci+1 : 63)*112896;
        __builtin_memcpy(nv, wn, 36);
        const float* pb_ = pbase + (size_t)ci*441;
        UNR for (int b=0;b<16;++b) {
            const float* q = pb_ + (size_t)b*451584;   // b*1024*441
            float a = acc[b];
            UNR for (int k=0;k<9;++k) a = fmaf(q[k], wv[k], a);
            acc[b] = a;
        }
        UNR for (int k=0;k<9;++k) wv[k] = nv[k];
    }
    UNR for (int b=0;b<16;++b)
        part[(((size_t)(s*16+b))*49 + hw)*256 + o] = acc[b];
}

// part [s][b][hw][o] -> yact[b][o*49+hw] with bias + leaky relu
__global__ void lreduce_k(const float* __restrict__ part, const float* __restrict__ lcb,
                          float* __restrict__ yact) {
    int idx = blockIdx.x*256 + (int)threadIdx.x;  // 200704 exactly
    int o = idx & 255; int t = idx >> 8; int hw = t % 49; int b = t / 49;
    float sum = 0.f;
    UNR for (int s=0;s<16;++s) sum += part[(((size_t)(s*16+b))*49 + hw)*256 + o];
    sum += lcb[o*49 + hw];
    float v = (sum > 0.f) ? sum : 0.1f*sum;
    yact[b*12544 + o*49 + hw] = v;
}

// ---------------------------------------------------------------------------
// FC
// ---------------------------------------------------------------------------
__global__ __launch_bounds__(256)
void fc_k(const float* __restrict__ act, const float* __restrict__ fw,
          const float* __restrict__ fb, float* __restrict__ out) {
    __shared__ float alds[16][256];
    __shared__ float red[4][4][16];
    const int t = (int)threadIdx.x;
    const int o0 = blockIdx.x*4;
    float acc[4][16];
    UNR for (int oo=0;oo<4;++oo) UNR for (int b=0;b<16;++b) acc[oo][b]=0.f;

    for (int k0=0; k0<12544; k0+=256) {
        __syncthreads();
        UNR for (int b=0;b<16;++b) alds[b][t] = act[b*12544 + k0 + t];
        __syncthreads();
        float wv[4];
        UNR for (int oo=0;oo<4;++oo) {
            int o = o0+oo;
            wv[oo] = (o < 4949) ? fw[(size_t)o*12544 + k0 + t] : 0.f;
        }
        UNR for (int b=0;b<16;++b) {
            float av = alds[b][t];
            UNR for (int oo=0;oo<4;++oo) acc[oo][b] = fmaf(wv[oo], av, acc[oo][b]);
        }
    }
    UNR for (int oo=0;oo<4;++oo)
        UNR for (int b=0;b<16;++b) {
            float v = acc[oo][b];
            UNR for (int off=32; off; off>>=1) v += __shfl_xor(v, off, 64);
            acc[oo][b] = v;
        }
    const int wave = t>>6, lane = t&63;
    if (lane == 0)
        UNR for (int oo=0;oo<4;++oo)
            UNR for (int b=0;b<16;++b) red[wave][oo][b] = acc[oo][b];
    __syncthreads();
    if (t < 64) {
        int oo = t>>4, b = t&15;
        float v = red[0][oo][b]+red[1][oo][b]+red[2][oo][b]+red[3][oo][b];
        int o = o0+oo;
        if (o < 4949) out[b*4949 + o] = v + fb[o];
    }
}

// ---------------------------------------------------------------------------
extern "C" void kernel_launch(void* const* d_in, const int* in_sizes, int n_in,
                              void* d_out, int out_size, void* d_ws, size_t ws_size,
                              hipStream_t stream) {
    const float* x   = (const float*)d_in[0];
    const float* w1  = (const float*)d_in[1];
    const float* b1  = (const float*)d_in[2];
    const float* w3  = (const float*)d_in[3];
    const float* b3  = (const float*)d_in[4];
    const float* w4  = (const float*)d_in[5];
    const float* b4  = (const float*)d_in[6];
    const float* w7  = (const float*)d_in[7];
    const float* b7  = (const float*)d_in[8];
    const float* w8  = (const float*)d_in[9];
    const float* b8  = (const float*)d_in[10];
    const float* wu  = (const float*)d_in[11];
    const float* bu  = (const float*)d_in[12];
    const float* lcw = (const float*)d_in[13];
    const float* lcb = (const float*)d_in[14];
    const float* fw  = (const float*)d_in[15];
    const float* fb  = (const float*)d_in[16];
    float* out = (float*)d_out;

    // --- workspace carve (bytes, 256-aligned) ---
    char* base = (char*)d_ws;
    auto alloc = [&](size_t bytes) { char* p = base; base += (bytes + 255) & ~(size_t)255; return p; };
    ushort* X1  = (ushort*)alloc(16u*456*456*4*2);   // 26.6 MB (later reused as P)
    ushort* X3  = (ushort*)alloc(16u*114*114*64*2);  // 26.6 MB
    ushort* X4  = (ushort*)alloc(16u*56*56*192*2);   // 19.3 MB (later reused as part)
    ushort* X7  = (ushort*)alloc(16u*27*27*256*2);   // 6.0 MB (later reused as yact)
    ushort* X8  = (ushort*)alloc(16u*13*13*512*2);
    ushort* XU1 = (ushort*)alloc(16u*12*12*1024*2);
    ushort* XU2 = (ushort*)alloc(16u*11*11*1024*2);
    ushort* XU3 = (ushort*)alloc(16u*10*10*1024*2);
    ushort* W1b = (ushort*)alloc(64u*224*2);
    ushort* W3b = (ushort*)alloc(192u*576*2);
    ushort* W4b = (ushort*)alloc(256u*1728*2);
    ushort* W7b = (ushort*)alloc(512u*1024*2);
    ushort* W8b = (ushort*)alloc(1024u*2048*2);
    ushort* WUb = (ushort*)alloc(1024u*4096*2);
    float*  pp  = (float*)alloc(16u*1024*4*4);
    // aliased (lifetimes disjoint):
    float*  P    = (float*)X1;   // 28.9 MB over X1+X3 (both dead by then)
    float*  part = (float*)X4;   // 12.8 MB over X4 (dead)
    float*  yact = (float*)X7;   // 0.8 MB over X7 (dead)

    // --- prep ---
    hipMemsetAsync(X1, 0, 16u*456*456*4*2, stream);
    hipMemsetAsync(X3, 0, 16u*114*114*64*2, stream);
    x1build<<<12544, 256, 0, stream>>>(x, X1);
    wcvt1<<<56, 256, 0, stream>>>(w1, W1b);
    wcvt<64,3><<<432, 256, 0, stream>>>(w3, W3b, 192*576);
    wcvt<192,3><<<1728, 256, 0, stream>>>(w4, W4b, 256*1728);
    wcvt<256,2><<<2048, 256, 0, stream>>>(w7, W7b, 512*1024);
    wcvt<512,2><<<8192, 256, 0, stream>>>(w8, W8b, 1024*2048);
    wcvt<1024,2><<<16384, 256, 0, stream>>>(wu, WUb, 1024*4096);

    // --- conv chain (MFMA, fused pool, reg-pipelined K-loop) ---
    convmf<4,7,2,456,456,224,224,64, true,114,114,1,64, 4,true>
        <<<dim3(3136,1), 256, 0, stream>>>(X1, W1b, b1, X3);
    convmf<64,3,1,114,114,112,112,192, true,56,56,0,192, 4,false>
        <<<dim3(784,3), 256, 0, stream>>>(X3, W3b, b3, X4);
    convmf<192,3,1,56,56,54,54,256, true,27,27,0,256, 4,false>
        <<<dim3(183,4), 256, 0, stream>>>(X4, W4b, b4, X7);
    convmf<256,2,1,27,27,26,26,512, true,13,13,0,512, 1,false>
        <<<dim3(169,8), 64, 0, stream>>>(X7, W7b, b7, X8);
    convmf<512,2,1,13,13,12,12,1024, false,12,12,0,1024, 1,false>
        <<<dim3(36,16), 64, 0, stream>>>(X8, W8b, b8, XU1);
    convmf<1024,2,1,12,12,11,11,1024, false,11,11,0,1024, 1,false>
        <<<dim3(31,16), 64, 0, stream>>>(XU1, WUb, bu, XU2);
    convmf<1024,2,1,11,11,10,10,1024, false,10,10,0,1024, 1,false>
        <<<dim3(25,16), 64, 0, stream>>>(XU2, WUb, bu, XU3);

    // --- head (fp32) ---
    pool54_k<<<256, 256, 0, stream>>>(XU3, pp);
    buildP_k<<<28224, 256, 0, stream>>>(pp, P);
    lconv_k<<<784, 256, 0, stream>>>(P, lcw, part);
    lreduce_k<<<784, 256, 0, stream>>>(part, lcb, yact);
    fc_k<<<1238, 256, 0, stream>>>(yact, fw, fb, out);
}